// Round 11
// baseline (361.482 us; speedup 1.0000x reference)
//
#include <hip/hip_runtime.h>
#include <hip/hip_bf16.h>
#include <stdint.h>

#define N_NODES 50000
#define N_EDGES 800000
#define HID 128
#define NODE_IN 16
#define NODE_OUT 3
#define NODE_TILES 782     // ceil(50000 / 64)
#define SCAN_BLOCKS 196    // ceil(50000 / 256)
#define EDGE_BLOCKS 3125   // 800000 / 256, one edge per thread in k1
#define MFOLD_BLOCKS 192   // 3*16384 / 256
#define SWZA_BLOCKS 576    // 3*(32768+16384) / 256  (Mtmp-independent swizzles)
#define SWZB_BLOCKS 384    // 3*32768 / 256          (w1m, Mtmp-dependent)
#define EDBLOCKS 6250      // 50000 / 8 dest-blocks (8 dests per block, 32 lanes each)

typedef __attribute__((ext_vector_type(8))) short short8;
typedef __attribute__((ext_vector_type(4))) float f32x4;
typedef __attribute__((ext_vector_type(4))) unsigned int u32x4;

__device__ __forceinline__ unsigned short f2bf(float f) {
    union { float f; unsigned int u; } v; v.f = f;
    unsigned int u = v.u;
    u += 0x7fff + ((u >> 16) & 1);   // round-to-nearest-even
    return (unsigned short)(u >> 16);
}
__device__ __forceinline__ float bf2f(unsigned short s) {
    union { unsigned int u; float f; } v; v.u = ((unsigned int)s) << 16;
    return v.f;
}
__device__ __forceinline__ float bfu_lo(unsigned int u) {
    union { unsigned int u; float f; } v; v.u = u << 16; return v.f;
}
__device__ __forceinline__ float bfu_hi(unsigned int u) {
    union { unsigned int u; float f; } v; v.u = u & 0xffff0000u; return v.f;
}
// 2x f32 -> packed bf16 (RNE), single HW instruction on gfx950
__device__ __forceinline__ unsigned int cvt_pk_bf16(float lo, float hi) {
    unsigned int r;
    asm("v_cvt_pk_bf16_f32 %0, %1, %2" : "=v"(r) : "v"(lo), "v"(hi));
    return r;
}

// ---------------- K1: sharded hist (+rank) || M-fold || encoder+S/D-L0 || swizzles ----------------
// Hist: block b updates shard b&7 of cnt8 (one block-residue class per shard ->
// heuristically one XCD per shard; if device atomics can resolve in the owning
// L2 this lifts the RMW throughput ceiling; if memory-side, same cost as before).
// Encoder+SD blocks are self-contained (h tile in LDS -> MFMA -> S/D), with
// w1cat fragments gathered directly from edge_w1 f32 (L2-resident).
__global__ __launch_bounds__(256) void k1_fused(
    const int* __restrict__ colp, int* __restrict__ cnt8, int* __restrict__ rank,
    const float* __restrict__ edge_w2, const float* __restrict__ node_w1,
    const float* __restrict__ edge_b2,
    float* __restrict__ Mtmp, float* __restrict__ Vtmp,
    const float* __restrict__ x, const float* __restrict__ enc_w,
    const float* __restrict__ enc_b, unsigned short* __restrict__ h,
    const float* __restrict__ edge_w1, const float* __restrict__ node_w2,
    unsigned short* __restrict__ swz,
    const float* __restrict__ eb1,
    unsigned short* __restrict__ S, unsigned short* __restrict__ D) {
    __shared__ float wts[NODE_IN * HID];
    __shared__ float bts[HID];
    __shared__ float xs[64][NODE_IN];
    __shared__ unsigned short hs[64][136];
    int b = blockIdx.x, t = threadIdx.x;
    if (b < EDGE_BLOCKS) {
        int e = b * 256 + t;   // exact: 3125*256 = 800000
        int c = colp[e];
        rank[e] = atomicAdd(&cnt8[(size_t)(b & 7) * N_NODES + c], 1);
    } else if (b < EDGE_BLOCKS + MFOLD_BLOCKS) {
        int d = (b - EDGE_BLOCKS) * 256 + t;     // exact: 192*256 = 49152 = 3*16384
        int L = d / 16384, rem = d & 16383;
        int k = rem >> 7, n = rem & 127;
        const float* w2  = edge_w2 + (size_t)L * 16384;
        const float* w1b = node_w1 + (size_t)L * 32768 + 16384;   // bottom-half rows
        float acc = 0.f;
        #pragma unroll 4
        for (int j = 0; j < 128; j++) acc += w2[k * 128 + j] * w1b[j * 128 + n];
        Mtmp[d] = acc;
        if (k == 0) {
            const float* b2 = edge_b2 + (size_t)L * 128;
            float vv = 0.f;
            #pragma unroll 4
            for (int j = 0; j < 128; j++) vv += b2[j] * w1b[j * 128 + n];
            Vtmp[L * 128 + n] = vv;
        }
    } else if (b < EDGE_BLOCKS + MFOLD_BLOCKS + NODE_TILES) {
        // encoder + S/D layer 0, self-contained per tile (round-3 k3b structure)
        int b2 = b - EDGE_BLOCKS - MFOLD_BLOCKS;   // 0..781
        int wave = t >> 6, l = t & 63, q = l >> 4, l16 = l & 15;
        int nt0s = wave * 4;
        int n0 = b2 * 64;

        for (int i = t; i < NODE_IN * HID; i += 256) wts[i] = enc_w[i];
        if (t < HID) bts[t] = enc_b[t];
        for (int i = t; i < 64 * NODE_IN; i += 256) {
            int nl = i >> 4, ii = i & 15;
            int n = n0 + nl;
            xs[nl][ii] = (n < N_NODES) ? x[n * NODE_IN + ii] : 0.f;
        }
        // w1cat frags gathered from edge_w1 (layer 0) f32 directly
        short8 wr[4][4];
        #pragma unroll
        for (int kt = 0; kt < 4; kt++)
            #pragma unroll
            for (int i = 0; i < 4; i++) {
                int ccol = (nt0s + i) * 16 + l16;
                #pragma unroll
                for (int j = 0; j < 8; j++) {
                    int k = kt * 32 + ((l >> 4) << 3) + j;
                    float v = (ccol < 128) ? edge_w1[k * 128 + ccol]
                                           : edge_w1[(128 + k) * 128 + (ccol - 128)];
                    ((unsigned short*)&wr[kt][i])[j] = f2bf(v);
                }
            }
        __syncthreads();

        for (int o = t; o < 64 * HID; o += 256) {
            int nl = o >> 7, cc = o & 127;
            float acc = bts[cc];
            #pragma unroll
            for (int i = 0; i < NODE_IN; i++) acc += xs[nl][i] * wts[i * HID + cc];
            unsigned short hb = f2bf(acc);
            hs[nl][cc] = hb;
            int n = n0 + nl;
            if (n < N_NODES) h[n * HID + cc] = hb;
        }
        __syncthreads();

        f32x4 acc[4][4];
        #pragma unroll
        for (int g = 0; g < 4; g++)
            #pragma unroll
            for (int i = 0; i < 4; i++) acc[g][i] = (f32x4){0.f, 0.f, 0.f, 0.f};
        #pragma unroll
        for (int kt = 0; kt < 4; kt++) {
            #pragma unroll
            for (int g = 0; g < 4; g++) {
                short8 a = *(const short8*)&hs[g * 16 + l16][kt * 32 + q * 8];
                #pragma unroll
                for (int i = 0; i < 4; i++)
                    acc[g][i] = __builtin_amdgcn_mfma_f32_16x16x32_bf16(a, wr[kt][i], acc[g][i], 0, 0, 0);
            }
        }
        #pragma unroll
        for (int i = 0; i < 4; i++) {
            int cc = (nt0s + i) * 16 + l16;
            float badd = 0.f;
            if (cc >= 128) badd = eb1[cc - 128];   // fold edge_b1[L=0] into D
            #pragma unroll
            for (int g = 0; g < 4; g++)
                #pragma unroll
                for (int r = 0; r < 4; r++) {
                    int n = n0 + g * 16 + q * 4 + r;
                    if (n < N_NODES) {
                        unsigned short v = f2bf(acc[g][i][r] + badd);
                        if (cc < 128) S[n * HID + cc] = v;
                        else          D[n * HID + (cc - 128)] = v;
                    }
                }
        }
    } else {
        // Mtmp-independent weight swizzles: edge w1cat + node w2
        int d = (b - EDGE_BLOCKS - MFOLD_BLOCKS - NODE_TILES) * 256 + t;  // < 147456 exact
        int L = d / 49152, rem2 = d - L * 49152;
        unsigned short* base = swz + L * 98304;
        if (rem2 < 32768) {
            const float* w1 = edge_w1 + (size_t)L * 32768;
            int j = rem2 & 7, ll = (rem2 >> 3) & 63, tt = rem2 >> 9;
            int nt = tt & 15, kt = tt >> 4;
            int k = kt * 32 + ((ll >> 4) << 3) + j;
            int cc = nt * 16 + (ll & 15);
            float v = (cc < 128) ? w1[k * 128 + cc] : w1[(128 + k) * 128 + (cc - 128)];
            base[rem2] = f2bf(v);
        } else {
            int d2 = rem2 - 32768;   // [0,16384): node w2
            const float* src = node_w2 + (size_t)L * 16384;
            int j = d2 & 7, ll = (d2 >> 3) & 63, tt = d2 >> 9;
            int nt = tt & 7, kt = tt >> 3;
            int k = kt * 32 + ((ll >> 4) << 3) + j, n = (nt << 4) + (ll & 15);
            base[81920 + d2] = f2bf(src[k * 128 + n]);
        }
    }
}

// ---------------- K2a: shard-reduce + scan1 + w1m swizzle ----------------
// Scan blocks: total cnt per node from the 8 shards (writes base8 prefixes +
// cntt totals), then the usual block-level exclusive scan.
__global__ __launch_bounds__(256) void k2a_scan1_swizzle(
    const int* __restrict__ cnt8, int* __restrict__ base8, int* __restrict__ cntt,
    int* __restrict__ ex, int* __restrict__ bsums,
    const float* __restrict__ node_w1, const float* __restrict__ Mtmp,
    unsigned short* __restrict__ swz) {
    __shared__ int s[256];
    int b = blockIdx.x, t = threadIdx.x;
    if (b < SCAN_BLOCKS) {
        int i = b * 256 + t;
        int tot = 0;
        if (i < N_NODES) {
            #pragma unroll
            for (int s2 = 0; s2 < 8; s2++) {
                int v = cnt8[(size_t)s2 * N_NODES + i];
                base8[(size_t)s2 * N_NODES + i] = tot;
                tot += v;
            }
            cntt[i] = tot;
        }
        s[t] = tot;
        __syncthreads();
        for (int off = 1; off < 256; off <<= 1) {
            int u = (t >= off) ? s[t - off] : 0;
            __syncthreads();
            s[t] += u;
            __syncthreads();
        }
        if (i < N_NODES) ex[i] = s[t] - tot;
        if (t == 255) bsums[b] = s[255];
    } else {
        int d = (b - SCAN_BLOCKS) * 256 + t;   // < 98304 exact
        int L = d / 32768, d2 = d - L * 32768;
        unsigned short* base = swz + L * 98304;
        int j = d2 & 7, ll = (d2 >> 3) & 63, tt = d2 >> 9;
        int nt = tt & 7, kt = tt >> 3;
        int k = kt * 32 + ((ll >> 4) << 3) + j, n = (nt << 4) + (ll & 15);
        float v = (k < 128) ? node_w1[(size_t)L * 32768 + k * 128 + n]
                            : Mtmp[(size_t)L * 16384 + (k - 128) * 128 + n];
        base[49152 + d2] = f2bf(v);
    }
}

// ---------------- K3: scatter only (+ex2); pos = ex + ls + base8[shard] + rank ----------------
__global__ __launch_bounds__(256) void k3_scatter(
    const int* __restrict__ rowp, const int* __restrict__ colp,
    const int* __restrict__ ex, const int* __restrict__ bsums,
    const int* __restrict__ rank, const int* __restrict__ base8,
    int* __restrict__ rsrt, int* __restrict__ ex2) {
    __shared__ int sc[256];
    __shared__ int ls[SCAN_BLOCKS];
    int b = blockIdx.x, t = threadIdx.x;
    int v = (t < SCAN_BLOCKS) ? bsums[t] : 0;
    sc[t] = v;
    __syncthreads();
    for (int off = 1; off < 256; off <<= 1) {
        int u = (t >= off) ? sc[t - off] : 0;
        __syncthreads();
        sc[t] += u;
        __syncthreads();
    }
    if (t < SCAN_BLOCKS) ls[t] = sc[t] - v;
    __syncthreads();

    if (b < SCAN_BLOCKS) {
        int i = b * 256 + t;
        if (i < N_NODES) ex2[i] = ex[i] + ls[b];
    }
    int e = b * 256 + t;   // exact 800000
    int c = colp[e];
    int sh = b & 7;        // shard = block residue (matches k1 hist)
    int pos = ex[c] + ls[c >> 8] + base8[(size_t)sh * N_NODES + c] + rank[e];
    rsrt[pos] = rowp[e];   // dest implied by position
}

// ---------------- edge: 32-lane dest groups, depth-4 2-stage pipeline ----------------
__global__ __launch_bounds__(256, 8) void edge_kernel(
    const unsigned short* __restrict__ S, const unsigned short* __restrict__ D,
    const int* __restrict__ rsrt, const int* __restrict__ ex2,
    unsigned short* __restrict__ aggB)
{
    int t = threadIdx.x;
    int g32 = t >> 5, ch = t & 31;   // 8 dests/block; lane covers channels ch*4..+3

    // XCD-chunked bijective mapping over EDBLOCKS dest-blocks
    const int q = EDBLOCKS / 8, r = EDBLOCKS % 8;   // 781, 2
    int xcd = blockIdx.x & 7, slot = blockIdx.x >> 3;
    int cntx = q + (xcd < r);
    if (slot >= cntx) return;
    int myb = xcd * q + (xcd < r ? xcd : r) + slot;

    int d = myb * 8 + g32;   // exact: 6250*8 = 50000
    int e0 = ex2[d];
    int e1 = (d < N_NODES - 1) ? ex2[d + 1] : N_EDGES;

    int2 dv = *(const int2*)(D + (size_t)d * HID + ch * 4);
    float dr0 = bfu_lo((unsigned int)dv.x), dr1 = bfu_hi((unsigned int)dv.x);
    float dr2 = bfu_lo((unsigned int)dv.y), dr3 = bfu_hi((unsigned int)dv.y);
    float a0 = 0.f, a1 = 0.f, a2 = 0.f, a3 = 0.f;

    auto Srow = [&](int rn) -> int2 {
        return *(const int2*)(S + (size_t)rn * HID + ch * 4);
    };
    auto accum = [&](int2 sv) {
        float v0 = bfu_lo((unsigned int)sv.x) + dr0;
        float v1 = bfu_hi((unsigned int)sv.x) + dr1;
        float v2 = bfu_lo((unsigned int)sv.y) + dr2;
        float v3 = bfu_hi((unsigned int)sv.y) + dr3;
        a0 += v0 > 0.f ? v0 : 0.f;
        a1 += v1 > 0.f ? v1 : 0.f;
        a2 += v2 > 0.f ? v2 : 0.f;
        a3 += v3 > 0.f ? v3 : 0.f;
    };
    const int2 z = make_int2(0, 0);

    int2 c0 = z, c1 = z, c2 = z, c3 = z;
    int rb0 = 0, rb1 = 0, rb2 = 0, rb3 = 0;
    {
        int ra0 = (e0     < e1) ? rsrt[e0]     : 0;
        int ra1 = (e0 + 1 < e1) ? rsrt[e0 + 1] : 0;
        int ra2 = (e0 + 2 < e1) ? rsrt[e0 + 2] : 0;
        int ra3 = (e0 + 3 < e1) ? rsrt[e0 + 3] : 0;
        rb0 = (e0 + 4 < e1) ? rsrt[e0 + 4] : 0;
        rb1 = (e0 + 5 < e1) ? rsrt[e0 + 5] : 0;
        rb2 = (e0 + 6 < e1) ? rsrt[e0 + 6] : 0;
        rb3 = (e0 + 7 < e1) ? rsrt[e0 + 7] : 0;
        if (e0     < e1) c0 = Srow(ra0);
        if (e0 + 1 < e1) c1 = Srow(ra1);
        if (e0 + 2 < e1) c2 = Srow(ra2);
        if (e0 + 3 < e1) c3 = Srow(ra3);
    }

    int e = e0;
    while (e + 12 <= e1) {
        int m0 = rsrt[e + 8], m1 = rsrt[e + 9];
        int2 f0 = Srow(rb0), f1 = Srow(rb1);
        accum(c0); accum(c1);
        int m2 = rsrt[e + 10], m3 = rsrt[e + 11];
        int2 f2 = Srow(rb2), f3 = Srow(rb3);
        accum(c2); accum(c3);
        c0 = f0; c1 = f1; c2 = f2; c3 = f3;
        rb0 = m0; rb1 = m1; rb2 = m2; rb3 = m3;
        e += 4;
    }
    int rem = e1 - e;   // 0..11
    if (rem > 0) accum(c0);
    if (rem > 1) accum(c1);
    if (rem > 2) accum(c2);
    if (rem > 3) accum(c3);
    if (rem > 4) accum(Srow(rb0));
    if (rem > 5) accum(Srow(rb1));
    if (rem > 6) accum(Srow(rb2));
    if (rem > 7) accum(Srow(rb3));
    for (int j = 8; j < rem; j++) accum(Srow(rsrt[e + j]));

    int2 o = make_int2((int)cvt_pk_bf16(a0, a1), (int)cvt_pk_bf16(a2, a3));
    *(int2*)(aggB + (size_t)d * HID + ch * 4) = o;
}

// ---------------- node MLP (folded GEMM1) + residual + (next S/D | decoder) ----------------
template<int LAST>
__global__ __launch_bounds__(256, 4) void node_kernel(
    unsigned short* __restrict__ h, const unsigned short* __restrict__ aggB,
    const int* __restrict__ cnt,
    const unsigned short* __restrict__ w1m_s, const float* __restrict__ b1,
    const float* __restrict__ vfold,
    const unsigned short* __restrict__ w2s, const float* __restrict__ b2,
    const unsigned short* __restrict__ w1c_next, const float* __restrict__ eb1n,
    unsigned short* __restrict__ S, unsigned short* __restrict__ D,
    const float* __restrict__ dec_w, const float* __restrict__ dec_b, float* __restrict__ out)
{
    __shared__ unsigned short in_h[64][136];   // old h -> new h after residual
    __shared__ unsigned short in_a[64][136];   // bf16 agg; reused as hid after GEMM1
    __shared__ int cnt_s[64];
    __shared__ float dw[HID * NODE_OUT];
    __shared__ float db[NODE_OUT];
    int t = threadIdx.x, wave = t >> 6, l = t & 63, q = l >> 4, l16 = l & 15;
    int nt0 = wave * 2, nt0s = wave * 4;
    int n0 = blockIdx.x * 64;

    if (LAST) {
        for (int i = t; i < HID * NODE_OUT; i += 256) dw[i] = dec_w[i];
        if (t < NODE_OUT) db[t] = dec_b[t];
    }

    // stage: h -> in_h, aggB(bf16) -> in_a, cnt
    #pragma unroll
    for (int it = 0; it < 8; it++) {
        int g = it * 256 + t;
        int nl = g >> 5, sub = g & 31, half = sub >> 4, li = sub & 15;
        int n = n0 + nl;
        short8 v = (short8){0, 0, 0, 0, 0, 0, 0, 0};
        if (n < N_NODES) {
            if (half == 0) v = *(const short8*)(h + (size_t)n * HID + li * 8);
            else           v = *(const short8*)(aggB + (size_t)n * HID + li * 8);
        }
        if (half == 0) *(short8*)&in_h[nl][li * 8] = v;
        else           *(short8*)&in_a[nl][li * 8] = v;
    }
    if (t < 64) cnt_s[t] = (n0 + t < N_NODES) ? cnt[n0 + t] : 0;
    __syncthreads();

    float b1r0 = b1[nt0 * 16 + l16], b1r1 = b1[(nt0 + 1) * 16 + l16];
    float vr0 = vfold[nt0 * 16 + l16], vr1 = vfold[(nt0 + 1) * 16 + l16];
    float b2r0 = b2[nt0 * 16 + l16], b2r1 = b2[(nt0 + 1) * 16 + l16];

    // GEMM1 (K=256, B = [W1top; M] folded): h@W1top + agg@M
    f32x4 acc[4][2];
    #pragma unroll
    for (int g = 0; g < 4; g++)
        #pragma unroll
        for (int j = 0; j < 2; j++) acc[g][j] = (f32x4){0.f, 0.f, 0.f, 0.f};
    #pragma unroll
    for (int kt = 0; kt < 8; kt++) {
        short8 b0 = *(const short8*)(w1m_s + ((kt * 8 + nt0)     * 64 + l) * 8);
        short8 b1v = *(const short8*)(w1m_s + ((kt * 8 + nt0 + 1) * 64 + l) * 8);
        #pragma unroll
        for (int g = 0; g < 4; g++) {
            short8 a = (kt < 4) ? *(const short8*)&in_h[g * 16 + l16][kt * 32 + q * 8]
                                : *(const short8*)&in_a[g * 16 + l16][(kt - 4) * 32 + q * 8];
            acc[g][0] = __builtin_amdgcn_mfma_f32_16x16x32_bf16(a, b0, acc[g][0], 0, 0, 0);
            acc[g][1] = __builtin_amdgcn_mfma_f32_16x16x32_bf16(a, b1v, acc[g][1], 0, 0, 0);
        }
    }
    __syncthreads();   // all in_a reads complete before hid overwrite

    // epilogue: + b1 + deg*v -> relu -> hid (aliases in_a)
    #pragma unroll
    for (int j = 0; j < 2; j++) {
        float bv = j ? b1r1 : b1r0;
        float vv = j ? vr1 : vr0;
        #pragma unroll
        for (int g = 0; g < 4; g++)
            #pragma unroll
            for (int r = 0; r < 4; r++) {
                int m2 = g * 16 + q * 4 + r;
                float v = acc[g][j][r] + bv + (float)cnt_s[m2] * vv;
                v = v > 0.f ? v : 0.f;
                in_a[m2][(nt0 + j) * 16 + l16] = f2bf(v);
            }
    }
    __syncthreads();

    // GEMM2n (K=128) -> residual -> h + in_h
    f32x4 acc2[4][2];
    #pragma unroll
    for (int g = 0; g < 4; g++)
        #pragma unroll
        for (int j = 0; j < 2; j++) acc2[g][j] = (f32x4){0.f, 0.f, 0.f, 0.f};
    #pragma unroll
    for (int kt = 0; kt < 4; kt++) {
        short8 b0 = *(const short8*)(w2s + ((kt * 8 + nt0)     * 64 + l) * 8);
        short8 b1v = *(const short8*)(w2s + ((kt * 8 + nt0 + 1) * 64 + l) * 8);
        #pragma unroll
        for (int g = 0; g < 4; g++) {
            short8 a = *(const short8*)&in_a[g * 16 + l16][kt * 32 + q * 8];
            acc2[g][0] = __builtin_amdgcn_mfma_f32_16x16x32_bf16(a, b0, acc2[g][0], 0, 0, 0);
            acc2[g][1] = __builtin_amdgcn_mfma_f32_16x16x32_bf16(a, b1v, acc2[g][1], 0, 0, 0);
        }
    }
    #pragma unroll
    for (int j = 0; j < 2; j++) {
        float bv = j ? b2r1 : b2r0;
        #pragma unroll
        for (int g = 0; g < 4; g++)
            #pragma unroll
            for (int r = 0; r < 4; r++) {
                float v = acc2[g][j][r] + bv;
                int m2 = g * 16 + q * 4 + r;
                int n = n0 + m2;
                if (n < N_NODES) {
                    int c = (nt0 + j) * 16 + l16;
                    unsigned short nh = f2bf(bf2f(in_h[m2][c]) + v);   // residual (same-thread cell)
                    if (!LAST) h[n * HID + c] = nh;
                    in_h[m2][c] = nh;
                }
            }
    }
    __syncthreads();

    if (!LAST) {
        // next-layer S/D from new h (in_h); D gets +edge_b1[L+1] folded
        #pragma unroll
        for (int p = 0; p < 2; p++) {
            short8 wr[4][2];
            #pragma unroll
            for (int kt = 0; kt < 4; kt++) {
                wr[kt][0] = *(const short8*)(w1c_next + ((kt * 16 + nt0s + p * 2)     * 64 + l) * 8);
                wr[kt][1] = *(const short8*)(w1c_next + ((kt * 16 + nt0s + p * 2 + 1) * 64 + l) * 8);
            }
            f32x4 accs[4][2];
            #pragma unroll
            for (int g = 0; g < 4; g++)
                #pragma unroll
                for (int i = 0; i < 2; i++) accs[g][i] = (f32x4){0.f, 0.f, 0.f, 0.f};
            #pragma unroll
            for (int kt = 0; kt < 4; kt++) {
                #pragma unroll
                for (int g = 0; g < 4; g++) {
                    short8 a = *(const short8*)&in_h[g * 16 + l16][kt * 32 + q * 8];
                    accs[g][0] = __builtin_amdgcn_mfma_f32_16x16x32_bf16(a, wr[kt][0], accs[g][0], 0, 0, 0);
                    accs[g][1] = __builtin_amdgcn_mfma_f32_16x16x32_bf16(a, wr[kt][1], accs[g][1], 0, 0, 0);
                }
            }
            #pragma unroll
            for (int i = 0; i < 2; i++) {
                int c = (nt0s + p * 2 + i) * 16 + l16;
                float badd = 0.f;
                if (c >= 128) badd = eb1n[c - 128];
                #pragma unroll
                for (int g = 0; g < 4; g++)
                    #pragma unroll
                    for (int r = 0; r < 4; r++) {
                        int n = n0 + g * 16 + q * 4 + r;
                        if (n < N_NODES) {
                            unsigned short v = f2bf(accs[g][i][r] + badd);
                            if (c < 128) S[n * HID + c] = v;
                            else         D[n * HID + (c - 128)] = v;
                        }
                    }
            }
        }
    } else {
        // decoder: out = new_h @ dec_w + dec_b
        if (t < 64 * NODE_OUT) {
            int nl = t / 3, o = t - 3 * nl;
            int n = n0 + nl;
            if (n < N_NODES) {
                float a = db[o];
                #pragma unroll 4
                for (int k = 0; k < HID; k++) a += bf2f(in_h[nl][k]) * dw[k * 3 + o];
                out[n * 3 + o] = a;
            }
        }
    }
}

extern "C" void kernel_launch(void* const* d_in, const int* in_sizes, int n_in,
                              void* d_out, int out_size, void* d_ws, size_t ws_size,
                              hipStream_t stream) {
    const float* x       = (const float*)d_in[0];
    const int*   ei      = (const int*)d_in[1];
    const float* enc_w   = (const float*)d_in[2];
    const float* enc_b   = (const float*)d_in[3];
    const float* dec_w   = (const float*)d_in[4];
    const float* dec_b   = (const float*)d_in[5];
    const float* edge_w1 = (const float*)d_in[6];
    const float* edge_b1 = (const float*)d_in[7];
    const float* edge_w2 = (const float*)d_in[8];
    const float* edge_b2 = (const float*)d_in[9];
    const float* node_w1 = (const float*)d_in[10];
    const float* node_b1 = (const float*)d_in[11];
    const float* node_w2 = (const float*)d_in[12];
    const float* node_b2 = (const float*)d_in[13];

    char* ws = (char*)d_ws;
    unsigned short* h    = (unsigned short*)ws;                    // 12.8 MB
    unsigned short* aggB = (unsigned short*)(ws + 12800000);       // 12.8 MB (bf16 agg)
    unsigned short* swz  = (unsigned short*)(ws + 25600000);       // 589,824 B
    int* cnt8            = (int*)(ws + 26189824);                  // 1.6 MB (8 shards)
    int* base8           = (int*)(ws + 27789824);                  // 1.6 MB
    int* cntt            = (int*)(ws + 29389824);                  // 200,000 B (totals)
    int* ex              = (int*)(ws + 29589824);                  // 200,000 B
    int* bsums           = (int*)(ws + 29789824);                  // 1,024 B
    int* rsrt            = (int*)(ws + 29790848);                  // 3.2 MB
    unsigned short* Sbuf = (unsigned short*)(ws + 32990848);       // 12.8 MB
    unsigned short* Dbuf = (unsigned short*)(ws + 45790848);       // 12.8 MB
    float* Mtmp          = (float*)(ws + 58590848);                // 196,608 B
    float* Vtmp          = (float*)(ws + 58787456);                // 1,536 B
    int* ex2             = (int*)(ws + 58788992);                  // 200,000 B
    int* rank            = (int*)(ws + 58988992);                  // 3.2 MB -> end 62,188,992

    const int* rowp = ei;            // edge_index[0] = source
    const int* colp = ei + N_EDGES;  // edge_index[1] = destination

    hipMemsetAsync(cnt8, 0, (size_t)8 * N_NODES * 4, stream);

    k1_fused<<<EDGE_BLOCKS + MFOLD_BLOCKS + NODE_TILES + SWZA_BLOCKS, 256, 0, stream>>>(
        colp, cnt8, rank, edge_w2, node_w1, edge_b2, Mtmp, Vtmp,
        x, enc_w, enc_b, h, edge_w1, node_w2, swz,
        edge_b1 /*fold L0 bias into D*/, Sbuf, Dbuf);
    k2a_scan1_swizzle<<<SCAN_BLOCKS + SWZB_BLOCKS, 256, 0, stream>>>(
        cnt8, base8, cntt, ex, bsums, node_w1, Mtmp, swz);
    k3_scatter<<<EDGE_BLOCKS, 256, 0, stream>>>(
        rowp, colp, ex, bsums, rank, base8, rsrt, ex2);

    for (int L = 0; L < 3; L++) {
        unsigned short* base = swz + (size_t)L * 98304;
        unsigned short* next = swz + (size_t)(L + 1) * 98304;   // w1cat of next layer
        edge_kernel<<<6256, 256, 0, stream>>>(Sbuf, Dbuf, rsrt, ex2, aggB);
        if (L < 2) {
            node_kernel<0><<<NODE_TILES, 256, 0, stream>>>(
                h, aggB, cntt,
                base + 49152, node_b1 + (size_t)L * HID, Vtmp + (size_t)L * HID,
                base + 81920, node_b2 + (size_t)L * HID,
                next, edge_b1 + (size_t)(L + 1) * HID, Sbuf, Dbuf, dec_w, dec_b, (float*)d_out);
        } else {
            node_kernel<1><<<NODE_TILES, 256, 0, stream>>>(
                h, aggB, cntt,
                base + 49152, node_b1 + (size_t)L * HID, Vtmp + (size_t)L * HID,
                base + 81920, node_b2 + (size_t)L * HID,
                base /*unused*/, edge_b1 /*unused*/, Sbuf, Dbuf, dec_w, dec_b, (float*)d_out);
        }
    }
}

// Round 12
// 349.394 us; speedup vs baseline: 1.0346x; 1.0346x over previous
//
#include <hip/hip_runtime.h>
#include <hip/hip_bf16.h>
#include <stdint.h>

#define N_NODES 50000
#define N_EDGES 800000
#define HID 128
#define NODE_IN 16
#define NODE_OUT 3
#define NODE_TILES 782     // ceil(50000 / 64)
#define SCAN_BLOCKS 196    // ceil(50000 / 256)
#define EDGE_BLOCKS 3125   // 800000 / 256, one edge per thread in k1
#define MFOLD_BLOCKS 192   // 3*16384 / 256
#define SWZA_BLOCKS 576    // 3*(32768+16384) / 256  (Mtmp-independent swizzles)
#define SWZB_BLOCKS 384    // 3*32768 / 256          (w1m, Mtmp-dependent)
#define EDBLOCKS 6250      // 50000 / 8 dest-blocks (8 dests per block, 32 lanes each)

typedef __attribute__((ext_vector_type(8))) short short8;
typedef __attribute__((ext_vector_type(4))) float f32x4;
typedef __attribute__((ext_vector_type(4))) unsigned int u32x4;

__device__ __forceinline__ unsigned short f2bf(float f) {
    union { float f; unsigned int u; } v; v.f = f;
    unsigned int u = v.u;
    u += 0x7fff + ((u >> 16) & 1);   // round-to-nearest-even
    return (unsigned short)(u >> 16);
}
__device__ __forceinline__ float bf2f(unsigned short s) {
    union { unsigned int u; float f; } v; v.u = ((unsigned int)s) << 16;
    return v.f;
}
__device__ __forceinline__ float bfu_lo(unsigned int u) {
    union { unsigned int u; float f; } v; v.u = u << 16; return v.f;
}
__device__ __forceinline__ float bfu_hi(unsigned int u) {
    union { unsigned int u; float f; } v; v.u = u & 0xffff0000u; return v.f;
}
// 2x f32 -> packed bf16 (RNE), single HW instruction on gfx950
__device__ __forceinline__ unsigned int cvt_pk_bf16(float lo, float hi) {
    unsigned int r;
    asm("v_cvt_pk_bf16_f32 %0, %1, %2" : "=v"(r) : "v"(lo), "v"(hi));
    return r;
}

// ---------------- K1: sharded hist (+rank) || M-fold || encoder || swizzles ----------------
// LEAN branches only (round-11 lesson: VGPR/LDS alloc is per-kernel, the
// fattest branch taxes every block -- keep MFMA work OUT of k1).
// Hist shard = block residue b&7 (matches HW XCD round-robin); the only change
// vs the unsharded round-10 hist is the cnt address -- a clean A/B for whether
// device atomics resolve faster when each line is touched by one XCD only.
__global__ __launch_bounds__(256) void k1_fused(
    const int* __restrict__ colp, int* __restrict__ cnt8, int* __restrict__ rank,
    const float* __restrict__ edge_w2, const float* __restrict__ node_w1,
    const float* __restrict__ edge_b2,
    float* __restrict__ Mtmp, float* __restrict__ Vtmp,
    const float* __restrict__ x, const float* __restrict__ enc_w,
    const float* __restrict__ enc_b, unsigned short* __restrict__ h,
    const float* __restrict__ edge_w1, const float* __restrict__ node_w2,
    unsigned short* __restrict__ swz) {
    __shared__ float wts[NODE_IN * HID];
    __shared__ float bts[HID];
    __shared__ float xs[64][NODE_IN];
    int b = blockIdx.x, t = threadIdx.x;
    if (b < EDGE_BLOCKS) {
        int e = b * 256 + t;   // exact: 3125*256 = 800000
        int c = colp[e];
        rank[e] = atomicAdd(&cnt8[(size_t)(b & 7) * N_NODES + c], 1);
    } else if (b < EDGE_BLOCKS + MFOLD_BLOCKS) {
        int d = (b - EDGE_BLOCKS) * 256 + t;     // exact: 192*256 = 49152 = 3*16384
        int L = d / 16384, rem = d & 16383;
        int k = rem >> 7, n = rem & 127;
        const float* w2  = edge_w2 + (size_t)L * 16384;
        const float* w1b = node_w1 + (size_t)L * 32768 + 16384;   // bottom-half rows
        float acc = 0.f;
        #pragma unroll 4
        for (int j = 0; j < 128; j++) acc += w2[k * 128 + j] * w1b[j * 128 + n];
        Mtmp[d] = acc;
        if (k == 0) {
            const float* b2 = edge_b2 + (size_t)L * 128;
            float vv = 0.f;
            #pragma unroll 4
            for (int j = 0; j < 128; j++) vv += b2[j] * w1b[j * 128 + n];
            Vtmp[L * 128 + n] = vv;
        }
    } else if (b < EDGE_BLOCKS + MFOLD_BLOCKS + NODE_TILES) {
        // encoder: h = x @ enc_w + enc_b (bf16 store)
        int b2 = b - EDGE_BLOCKS - MFOLD_BLOCKS;   // 0..781
        int n0 = b2 * 64;
        for (int i = t; i < NODE_IN * HID; i += 256) wts[i] = enc_w[i];
        if (t < HID) bts[t] = enc_b[t];
        for (int i = t; i < 64 * NODE_IN; i += 256) {
            int nl = i >> 4, ii = i & 15;
            int n = n0 + nl;
            xs[nl][ii] = (n < N_NODES) ? x[n * NODE_IN + ii] : 0.f;
        }
        __syncthreads();
        for (int o = t; o < 64 * HID; o += 256) {
            int nl = o >> 7, cc = o & 127;
            float acc = bts[cc];
            #pragma unroll
            for (int i = 0; i < NODE_IN; i++) acc += xs[nl][i] * wts[i * HID + cc];
            int n = n0 + nl;
            if (n < N_NODES) h[n * HID + cc] = f2bf(acc);
        }
    } else {
        // Mtmp-independent weight swizzles: edge w1cat + node w2
        int d = (b - EDGE_BLOCKS - MFOLD_BLOCKS - NODE_TILES) * 256 + t;  // < 147456 exact
        int L = d / 49152, rem2 = d - L * 49152;
        unsigned short* base = swz + L * 98304;
        if (rem2 < 32768) {
            const float* w1 = edge_w1 + (size_t)L * 32768;
            int j = rem2 & 7, ll = (rem2 >> 3) & 63, tt = rem2 >> 9;
            int nt = tt & 15, kt = tt >> 4;
            int k = kt * 32 + ((ll >> 4) << 3) + j;
            int cc = nt * 16 + (ll & 15);
            float v = (cc < 128) ? w1[k * 128 + cc] : w1[(128 + k) * 128 + (cc - 128)];
            base[rem2] = f2bf(v);
        } else {
            int d2 = rem2 - 32768;   // [0,16384): node w2
            const float* src = node_w2 + (size_t)L * 16384;
            int j = d2 & 7, ll = (d2 >> 3) & 63, tt = d2 >> 9;
            int nt = tt & 7, kt = tt >> 3;
            int k = kt * 32 + ((ll >> 4) << 3) + j, n = (nt << 4) + (ll & 15);
            base[81920 + d2] = f2bf(src[k * 128 + n]);
        }
    }
}

// ---------------- K2a: shard-reduce + scan1 + w1m swizzle ----------------
__global__ __launch_bounds__(256) void k2a_scan1_swizzle(
    const int* __restrict__ cnt8, int* __restrict__ base8, int* __restrict__ cntt,
    int* __restrict__ ex, int* __restrict__ bsums,
    const float* __restrict__ node_w1, const float* __restrict__ Mtmp,
    unsigned short* __restrict__ swz) {
    __shared__ int s[256];
    int b = blockIdx.x, t = threadIdx.x;
    if (b < SCAN_BLOCKS) {
        int i = b * 256 + t;
        int tot = 0;
        if (i < N_NODES) {
            #pragma unroll
            for (int s2 = 0; s2 < 8; s2++) {
                int v = cnt8[(size_t)s2 * N_NODES + i];
                base8[(size_t)s2 * N_NODES + i] = tot;
                tot += v;
            }
            cntt[i] = tot;
        }
        s[t] = tot;
        __syncthreads();
        for (int off = 1; off < 256; off <<= 1) {
            int u = (t >= off) ? s[t - off] : 0;
            __syncthreads();
            s[t] += u;
            __syncthreads();
        }
        if (i < N_NODES) ex[i] = s[t] - tot;
        if (t == 255) bsums[b] = s[255];
    } else {
        int d = (b - SCAN_BLOCKS) * 256 + t;   // < 98304 exact
        int L = d / 32768, d2 = d - L * 32768;
        unsigned short* base = swz + L * 98304;
        int j = d2 & 7, ll = (d2 >> 3) & 63, tt = d2 >> 9;
        int nt = tt & 7, kt = tt >> 3;
        int k = kt * 32 + ((ll >> 4) << 3) + j, n = (nt << 4) + (ll & 15);
        float v = (k < 128) ? node_w1[(size_t)L * 32768 + k * 128 + n]
                            : Mtmp[(size_t)L * 16384 + (k - 128) * 128 + n];
        base[49152 + d2] = f2bf(v);
    }
}

// ---------------- K3: scatter (+ex2, shard-aware pos) || S/D layer-0 generation ----------------
__global__ __launch_bounds__(256) void k3_scatter_sd(
    const int* __restrict__ rowp, const int* __restrict__ colp,
    const int* __restrict__ ex, const int* __restrict__ bsums,
    const int* __restrict__ rank, const int* __restrict__ base8,
    int* __restrict__ rsrt, int* __restrict__ ex2,
    const unsigned short* __restrict__ h, const unsigned short* __restrict__ w1c,
    const float* __restrict__ eb1,
    unsigned short* __restrict__ S, unsigned short* __restrict__ D) {
    __shared__ int sc[256];
    __shared__ int ls[SCAN_BLOCKS];
    __shared__ unsigned short hs[64][136];
    int b = blockIdx.x, t = threadIdx.x;
    if (b < EDGE_BLOCKS) {
        int v = (t < SCAN_BLOCKS) ? bsums[t] : 0;
        sc[t] = v;
        __syncthreads();
        for (int off = 1; off < 256; off <<= 1) {
            int u = (t >= off) ? sc[t - off] : 0;
            __syncthreads();
            sc[t] += u;
            __syncthreads();
        }
        if (t < SCAN_BLOCKS) ls[t] = sc[t] - v;
        __syncthreads();

        if (b < SCAN_BLOCKS) {
            int i = b * 256 + t;
            if (i < N_NODES) ex2[i] = ex[i] + ls[b];
        }
        int e = b * 256 + t;   // exact 800000
        int c = colp[e];
        int sh = b & 7;        // shard = block residue (matches k1 hist)
        int pos = ex[c] + ls[c >> 8] + base8[(size_t)sh * N_NODES + c] + rank[e];
        rsrt[pos] = rowp[e];   // dest implied by position
    } else {
        // S/D for layer 0 from h (D gets +edge_b1[0] folded)
        int b2 = b - EDGE_BLOCKS;   // 0..781
        int wave = t >> 6, l = t & 63, q = l >> 4, l16 = l & 15;
        int nt0s = wave * 4;
        int n0 = b2 * 64;
        for (int i = t; i < 64 * 16; i += 256) {
            int nl = i >> 4, li = i & 15;
            int n = n0 + nl;
            short8 v = (short8){0, 0, 0, 0, 0, 0, 0, 0};
            if (n < N_NODES) v = *(const short8*)(h + (size_t)n * HID + li * 8);
            *(short8*)&hs[nl][li * 8] = v;
        }
        short8 wr[4][4];
        #pragma unroll
        for (int kt = 0; kt < 4; kt++)
            #pragma unroll
            for (int i = 0; i < 4; i++)
                wr[kt][i] = *(const short8*)(w1c + ((kt * 16 + nt0s + i) * 64 + l) * 8);
        __syncthreads();

        f32x4 acc[4][4];
        #pragma unroll
        for (int g = 0; g < 4; g++)
            #pragma unroll
            for (int i = 0; i < 4; i++) acc[g][i] = (f32x4){0.f, 0.f, 0.f, 0.f};
        #pragma unroll
        for (int kt = 0; kt < 4; kt++) {
            #pragma unroll
            for (int g = 0; g < 4; g++) {
                short8 a = *(const short8*)&hs[g * 16 + l16][kt * 32 + q * 8];
                #pragma unroll
                for (int i = 0; i < 4; i++)
                    acc[g][i] = __builtin_amdgcn_mfma_f32_16x16x32_bf16(a, wr[kt][i], acc[g][i], 0, 0, 0);
            }
        }
        #pragma unroll
        for (int i = 0; i < 4; i++) {
            int cc = (nt0s + i) * 16 + l16;
            float badd = 0.f;
            if (cc >= 128) badd = eb1[cc - 128];
            #pragma unroll
            for (int g = 0; g < 4; g++)
                #pragma unroll
                for (int r = 0; r < 4; r++) {
                    int n = n0 + g * 16 + q * 4 + r;
                    if (n < N_NODES) {
                        unsigned short v = f2bf(acc[g][i][r] + badd);
                        if (cc < 128) S[n * HID + cc] = v;
                        else          D[n * HID + (cc - 128)] = v;
                    }
                }
        }
    }
}

// ---------------- edge: 32-lane dest groups, depth-4 2-stage pipeline ----------------
__global__ __launch_bounds__(256, 8) void edge_kernel(
    const unsigned short* __restrict__ S, const unsigned short* __restrict__ D,
    const int* __restrict__ rsrt, const int* __restrict__ ex2,
    unsigned short* __restrict__ aggB)
{
    int t = threadIdx.x;
    int g32 = t >> 5, ch = t & 31;   // 8 dests/block; lane covers channels ch*4..+3

    // XCD-chunked bijective mapping over EDBLOCKS dest-blocks
    const int q = EDBLOCKS / 8, r = EDBLOCKS % 8;   // 781, 2
    int xcd = blockIdx.x & 7, slot = blockIdx.x >> 3;
    int cntx = q + (xcd < r);
    if (slot >= cntx) return;
    int myb = xcd * q + (xcd < r ? xcd : r) + slot;

    int d = myb * 8 + g32;   // exact: 6250*8 = 50000
    int e0 = ex2[d];
    int e1 = (d < N_NODES - 1) ? ex2[d + 1] : N_EDGES;

    int2 dv = *(const int2*)(D + (size_t)d * HID + ch * 4);
    float dr0 = bfu_lo((unsigned int)dv.x), dr1 = bfu_hi((unsigned int)dv.x);
    float dr2 = bfu_lo((unsigned int)dv.y), dr3 = bfu_hi((unsigned int)dv.y);
    float a0 = 0.f, a1 = 0.f, a2 = 0.f, a3 = 0.f;

    auto Srow = [&](int rn) -> int2 {
        return *(const int2*)(S + (size_t)rn * HID + ch * 4);
    };
    auto accum = [&](int2 sv) {
        float v0 = bfu_lo((unsigned int)sv.x) + dr0;
        float v1 = bfu_hi((unsigned int)sv.x) + dr1;
        float v2 = bfu_lo((unsigned int)sv.y) + dr2;
        float v3 = bfu_hi((unsigned int)sv.y) + dr3;
        a0 += v0 > 0.f ? v0 : 0.f;
        a1 += v1 > 0.f ? v1 : 0.f;
        a2 += v2 > 0.f ? v2 : 0.f;
        a3 += v3 > 0.f ? v3 : 0.f;
    };
    const int2 z = make_int2(0, 0);

    int2 c0 = z, c1 = z, c2 = z, c3 = z;
    int rb0 = 0, rb1 = 0, rb2 = 0, rb3 = 0;
    {
        int ra0 = (e0     < e1) ? rsrt[e0]     : 0;
        int ra1 = (e0 + 1 < e1) ? rsrt[e0 + 1] : 0;
        int ra2 = (e0 + 2 < e1) ? rsrt[e0 + 2] : 0;
        int ra3 = (e0 + 3 < e1) ? rsrt[e0 + 3] : 0;
        rb0 = (e0 + 4 < e1) ? rsrt[e0 + 4] : 0;
        rb1 = (e0 + 5 < e1) ? rsrt[e0 + 5] : 0;
        rb2 = (e0 + 6 < e1) ? rsrt[e0 + 6] : 0;
        rb3 = (e0 + 7 < e1) ? rsrt[e0 + 7] : 0;
        if (e0     < e1) c0 = Srow(ra0);
        if (e0 + 1 < e1) c1 = Srow(ra1);
        if (e0 + 2 < e1) c2 = Srow(ra2);
        if (e0 + 3 < e1) c3 = Srow(ra3);
    }

    int e = e0;
    while (e + 12 <= e1) {
        int m0 = rsrt[e + 8], m1 = rsrt[e + 9];
        int2 f0 = Srow(rb0), f1 = Srow(rb1);
        accum(c0); accum(c1);
        int m2 = rsrt[e + 10], m3 = rsrt[e + 11];
        int2 f2 = Srow(rb2), f3 = Srow(rb3);
        accum(c2); accum(c3);
        c0 = f0; c1 = f1; c2 = f2; c3 = f3;
        rb0 = m0; rb1 = m1; rb2 = m2; rb3 = m3;
        e += 4;
    }
    int rem = e1 - e;   // 0..11
    if (rem > 0) accum(c0);
    if (rem > 1) accum(c1);
    if (rem > 2) accum(c2);
    if (rem > 3) accum(c3);
    if (rem > 4) accum(Srow(rb0));
    if (rem > 5) accum(Srow(rb1));
    if (rem > 6) accum(Srow(rb2));
    if (rem > 7) accum(Srow(rb3));
    for (int j = 8; j < rem; j++) accum(Srow(rsrt[e + j]));

    int2 o = make_int2((int)cvt_pk_bf16(a0, a1), (int)cvt_pk_bf16(a2, a3));
    *(int2*)(aggB + (size_t)d * HID + ch * 4) = o;
}

// ---------------- node MLP (folded GEMM1) + residual + (next S/D | decoder) ----------------
template<int LAST>
__global__ __launch_bounds__(256, 4) void node_kernel(
    unsigned short* __restrict__ h, const unsigned short* __restrict__ aggB,
    const int* __restrict__ cnt,
    const unsigned short* __restrict__ w1m_s, const float* __restrict__ b1,
    const float* __restrict__ vfold,
    const unsigned short* __restrict__ w2s, const float* __restrict__ b2,
    const unsigned short* __restrict__ w1c_next, const float* __restrict__ eb1n,
    unsigned short* __restrict__ S, unsigned short* __restrict__ D,
    const float* __restrict__ dec_w, const float* __restrict__ dec_b, float* __restrict__ out)
{
    __shared__ unsigned short in_h[64][136];   // old h -> new h after residual
    __shared__ unsigned short in_a[64][136];   // bf16 agg; reused as hid after GEMM1
    __shared__ int cnt_s[64];
    __shared__ float dw[HID * NODE_OUT];
    __shared__ float db[NODE_OUT];
    int t = threadIdx.x, wave = t >> 6, l = t & 63, q = l >> 4, l16 = l & 15;
    int nt0 = wave * 2, nt0s = wave * 4;
    int n0 = blockIdx.x * 64;

    if (LAST) {
        for (int i = t; i < HID * NODE_OUT; i += 256) dw[i] = dec_w[i];
        if (t < NODE_OUT) db[t] = dec_b[t];
    }

    // stage: h -> in_h, aggB(bf16) -> in_a, cnt
    #pragma unroll
    for (int it = 0; it < 8; it++) {
        int g = it * 256 + t;
        int nl = g >> 5, sub = g & 31, half = sub >> 4, li = sub & 15;
        int n = n0 + nl;
        short8 v = (short8){0, 0, 0, 0, 0, 0, 0, 0};
        if (n < N_NODES) {
            if (half == 0) v = *(const short8*)(h + (size_t)n * HID + li * 8);
            else           v = *(const short8*)(aggB + (size_t)n * HID + li * 8);
        }
        if (half == 0) *(short8*)&in_h[nl][li * 8] = v;
        else           *(short8*)&in_a[nl][li * 8] = v;
    }
    if (t < 64) cnt_s[t] = (n0 + t < N_NODES) ? cnt[n0 + t] : 0;
    __syncthreads();

    float b1r0 = b1[nt0 * 16 + l16], b1r1 = b1[(nt0 + 1) * 16 + l16];
    float vr0 = vfold[nt0 * 16 + l16], vr1 = vfold[(nt0 + 1) * 16 + l16];
    float b2r0 = b2[nt0 * 16 + l16], b2r1 = b2[(nt0 + 1) * 16 + l16];

    // GEMM1 (K=256, B = [W1top; M] folded): h@W1top + agg@M
    f32x4 acc[4][2];
    #pragma unroll
    for (int g = 0; g < 4; g++)
        #pragma unroll
        for (int j = 0; j < 2; j++) acc[g][j] = (f32x4){0.f, 0.f, 0.f, 0.f};
    #pragma unroll
    for (int kt = 0; kt < 8; kt++) {
        short8 b0 = *(const short8*)(w1m_s + ((kt * 8 + nt0)     * 64 + l) * 8);
        short8 b1v = *(const short8*)(w1m_s + ((kt * 8 + nt0 + 1) * 64 + l) * 8);
        #pragma unroll
        for (int g = 0; g < 4; g++) {
            short8 a = (kt < 4) ? *(const short8*)&in_h[g * 16 + l16][kt * 32 + q * 8]
                                : *(const short8*)&in_a[g * 16 + l16][(kt - 4) * 32 + q * 8];
            acc[g][0] = __builtin_amdgcn_mfma_f32_16x16x32_bf16(a, b0, acc[g][0], 0, 0, 0);
            acc[g][1] = __builtin_amdgcn_mfma_f32_16x16x32_bf16(a, b1v, acc[g][1], 0, 0, 0);
        }
    }
    __syncthreads();   // all in_a reads complete before hid overwrite

    // epilogue: + b1 + deg*v -> relu -> hid (aliases in_a)
    #pragma unroll
    for (int j = 0; j < 2; j++) {
        float bv = j ? b1r1 : b1r0;
        float vv = j ? vr1 : vr0;
        #pragma unroll
        for (int g = 0; g < 4; g++)
            #pragma unroll
            for (int r = 0; r < 4; r++) {
                int m2 = g * 16 + q * 4 + r;
                float v = acc[g][j][r] + bv + (float)cnt_s[m2] * vv;
                v = v > 0.f ? v : 0.f;
                in_a[m2][(nt0 + j) * 16 + l16] = f2bf(v);
            }
    }
    __syncthreads();

    // GEMM2n (K=128) -> residual -> h + in_h
    f32x4 acc2[4][2];
    #pragma unroll
    for (int g = 0; g < 4; g++)
        #pragma unroll
        for (int j = 0; j < 2; j++) acc2[g][j] = (f32x4){0.f, 0.f, 0.f, 0.f};
    #pragma unroll
    for (int kt = 0; kt < 4; kt++) {
        short8 b0 = *(const short8*)(w2s + ((kt * 8 + nt0)     * 64 + l) * 8);
        short8 b1v = *(const short8*)(w2s + ((kt * 8 + nt0 + 1) * 64 + l) * 8);
        #pragma unroll
        for (int g = 0; g < 4; g++) {
            short8 a = *(const short8*)&in_a[g * 16 + l16][kt * 32 + q * 8];
            acc2[g][0] = __builtin_amdgcn_mfma_f32_16x16x32_bf16(a, b0, acc2[g][0], 0, 0, 0);
            acc2[g][1] = __builtin_amdgcn_mfma_f32_16x16x32_bf16(a, b1v, acc2[g][1], 0, 0, 0);
        }
    }
    #pragma unroll
    for (int j = 0; j < 2; j++) {
        float bv = j ? b2r1 : b2r0;
        #pragma unroll
        for (int g = 0; g < 4; g++)
            #pragma unroll
            for (int r = 0; r < 4; r++) {
                float v = acc2[g][j][r] + bv;
                int m2 = g * 16 + q * 4 + r;
                int n = n0 + m2;
                if (n < N_NODES) {
                    int c = (nt0 + j) * 16 + l16;
                    unsigned short nh = f2bf(bf2f(in_h[m2][c]) + v);   // residual (same-thread cell)
                    if (!LAST) h[n * HID + c] = nh;
                    in_h[m2][c] = nh;
                }
            }
    }
    __syncthreads();

    if (!LAST) {
        // next-layer S/D from new h (in_h); D gets +edge_b1[L+1] folded
        #pragma unroll
        for (int p = 0; p < 2; p++) {
            short8 wr[4][2];
            #pragma unroll
            for (int kt = 0; kt < 4; kt++) {
                wr[kt][0] = *(const short8*)(w1c_next + ((kt * 16 + nt0s + p * 2)     * 64 + l) * 8);
                wr[kt][1] = *(const short8*)(w1c_next + ((kt * 16 + nt0s + p * 2 + 1) * 64 + l) * 8);
            }
            f32x4 accs[4][2];
            #pragma unroll
            for (int g = 0; g < 4; g++)
                #pragma unroll
                for (int i = 0; i < 2; i++) accs[g][i] = (f32x4){0.f, 0.f, 0.f, 0.f};
            #pragma unroll
            for (int kt = 0; kt < 4; kt++) {
                #pragma unroll
                for (int g = 0; g < 4; g++) {
                    short8 a = *(const short8*)&in_h[g * 16 + l16][kt * 32 + q * 8];
                    accs[g][0] = __builtin_amdgcn_mfma_f32_16x16x32_bf16(a, wr[kt][0], accs[g][0], 0, 0, 0);
                    accs[g][1] = __builtin_amdgcn_mfma_f32_16x16x32_bf16(a, wr[kt][1], accs[g][1], 0, 0, 0);
                }
            }
            #pragma unroll
            for (int i = 0; i < 2; i++) {
                int c = (nt0s + p * 2 + i) * 16 + l16;
                float badd = 0.f;
                if (c >= 128) badd = eb1n[c - 128];
                #pragma unroll
                for (int g = 0; g < 4; g++)
                    #pragma unroll
                    for (int r = 0; r < 4; r++) {
                        int n = n0 + g * 16 + q * 4 + r;
                        if (n < N_NODES) {
                            unsigned short v = f2bf(accs[g][i][r] + badd);
                            if (c < 128) S[n * HID + c] = v;
                            else         D[n * HID + (c - 128)] = v;
                        }
                    }
            }
        }
    } else {
        // decoder: out = new_h @ dec_w + dec_b
        if (t < 64 * NODE_OUT) {
            int nl = t / 3, o = t - 3 * nl;
            int n = n0 + nl;
            if (n < N_NODES) {
                float a = db[o];
                #pragma unroll 4
                for (int k = 0; k < HID; k++) a += bf2f(in_h[nl][k]) * dw[k * 3 + o];
                out[n * 3 + o] = a;
            }
        }
    }
}

extern "C" void kernel_launch(void* const* d_in, const int* in_sizes, int n_in,
                              void* d_out, int out_size, void* d_ws, size_t ws_size,
                              hipStream_t stream) {
    const float* x       = (const float*)d_in[0];
    const int*   ei      = (const int*)d_in[1];
    const float* enc_w   = (const float*)d_in[2];
    const float* enc_b   = (const float*)d_in[3];
    const float* dec_w   = (const float*)d_in[4];
    const float* dec_b   = (const float*)d_in[5];
    const float* edge_w1 = (const float*)d_in[6];
    const float* edge_b1 = (const float*)d_in[7];
    const float* edge_w2 = (const float*)d_in[8];
    const float* edge_b2 = (const float*)d_in[9];
    const float* node_w1 = (const float*)d_in[10];
    const float* node_b1 = (const float*)d_in[11];
    const float* node_w2 = (const float*)d_in[12];
    const float* node_b2 = (const float*)d_in[13];

    char* ws = (char*)d_ws;
    unsigned short* h    = (unsigned short*)ws;                    // 12.8 MB
    unsigned short* aggB = (unsigned short*)(ws + 12800000);       // 12.8 MB (bf16 agg)
    unsigned short* swz  = (unsigned short*)(ws + 25600000);       // 589,824 B
    int* cnt8            = (int*)(ws + 26189824);                  // 1.6 MB (8 shards)
    int* base8           = (int*)(ws + 27789824);                  // 1.6 MB
    int* cntt            = (int*)(ws + 29389824);                  // 200,000 B (totals)
    int* ex              = (int*)(ws + 29589824);                  // 200,000 B
    int* bsums           = (int*)(ws + 29789824);                  // 1,024 B
    int* rsrt            = (int*)(ws + 29790848);                  // 3.2 MB
    unsigned short* Sbuf = (unsigned short*)(ws + 32990848);       // 12.8 MB
    unsigned short* Dbuf = (unsigned short*)(ws + 45790848);       // 12.8 MB
    float* Mtmp          = (float*)(ws + 58590848);                // 196,608 B
    float* Vtmp          = (float*)(ws + 58787456);                // 1,536 B
    int* ex2             = (int*)(ws + 58788992);                  // 200,000 B
    int* rank            = (int*)(ws + 58988992);                  // 3.2 MB -> end 62,188,992

    const int* rowp = ei;            // edge_index[0] = source
    const int* colp = ei + N_EDGES;  // edge_index[1] = destination

    hipMemsetAsync(cnt8, 0, (size_t)8 * N_NODES * 4, stream);

    k1_fused<<<EDGE_BLOCKS + MFOLD_BLOCKS + NODE_TILES + SWZA_BLOCKS, 256, 0, stream>>>(
        colp, cnt8, rank, edge_w2, node_w1, edge_b2, Mtmp, Vtmp,
        x, enc_w, enc_b, h, edge_w1, node_w2, swz);
    k2a_scan1_swizzle<<<SCAN_BLOCKS + SWZB_BLOCKS, 256, 0, stream>>>(
        cnt8, base8, cntt, ex, bsums, node_w1, Mtmp, swz);
    k3_scatter_sd<<<EDGE_BLOCKS + NODE_TILES, 256, 0, stream>>>(
        rowp, colp, ex, bsums, rank, base8, rsrt, ex2,
        h, swz /*L0 w1cat*/, edge_b1 /*fold L0 bias into D*/, Sbuf, Dbuf);

    for (int L = 0; L < 3; L++) {
        unsigned short* base = swz + (size_t)L * 98304;
        unsigned short* next = swz + (size_t)(L + 1) * 98304;   // w1cat of next layer
        edge_kernel<<<6256, 256, 0, stream>>>(Sbuf, Dbuf, rsrt, ex2, aggB);
        if (L < 2) {
            node_kernel<0><<<NODE_TILES, 256, 0, stream>>>(
                h, aggB, cntt,
                base + 49152, node_b1 + (size_t)L * HID, Vtmp + (size_t)L * HID,
                base + 81920, node_b2 + (size_t)L * HID,
                next, edge_b1 + (size_t)(L + 1) * HID, Sbuf, Dbuf, dec_w, dec_b, (float*)d_out);
        } else {
            node_kernel<1><<<NODE_TILES, 256, 0, stream>>>(
                h, aggB, cntt,
                base + 49152, node_b1 + (size_t)L * HID, Vtmp + (size_t)L * HID,
                base + 81920, node_b2 + (size_t)L * HID,
                base /*unused*/, edge_b1 /*unused*/, Sbuf, Dbuf, dec_w, dec_b, (float*)d_out);
        }
    }
}

// Round 13
// 347.662 us; speedup vs baseline: 1.0397x; 1.0050x over previous
//
#include <hip/hip_runtime.h>
#include <hip/hip_bf16.h>
#include <stdint.h>

#define N_NODES 50000
#define N_EDGES 800000
#define HID 128
#define NODE_IN 16
#define NODE_OUT 3
#define NODE_TILES 782     // ceil(50000 / 64)
#define SCAN_BLOCKS 196    // ceil(50000 / 256)
#define EDGE_BLOCKS 3125   // 800000 / 256, one edge per thread in k1
#define MFOLD_BLOCKS 192   // 3*16384 / 256
#define SWZA_BLOCKS 576    // 3*(32768+16384) / 256  (Mtmp-independent swizzles)
#define SWZB_BLOCKS 384    // 3*32768 / 256          (w1m, Mtmp-dependent)
#define EDBLOCKS 6250      // 50000 / 8 dest-blocks (8 dests per block, 32 lanes each)

typedef __attribute__((ext_vector_type(8))) short short8;
typedef __attribute__((ext_vector_type(4))) float f32x4;
typedef __attribute__((ext_vector_type(4))) unsigned int u32x4;

__device__ __forceinline__ unsigned short f2bf(float f) {
    union { float f; unsigned int u; } v; v.f = f;
    unsigned int u = v.u;
    u += 0x7fff + ((u >> 16) & 1);   // round-to-nearest-even
    return (unsigned short)(u >> 16);
}
__device__ __forceinline__ float bf2f(unsigned short s) {
    union { unsigned int u; float f; } v; v.u = ((unsigned int)s) << 16;
    return v.f;
}
__device__ __forceinline__ float bfu_lo(unsigned int u) {
    union { unsigned int u; float f; } v; v.u = u << 16; return v.f;
}
__device__ __forceinline__ float bfu_hi(unsigned int u) {
    union { unsigned int u; float f; } v; v.u = u & 0xffff0000u; return v.f;
}
// 2x f32 -> packed bf16 (RNE), single HW instruction on gfx950
__device__ __forceinline__ unsigned int cvt_pk_bf16(float lo, float hi) {
    unsigned int r;
    asm("v_cvt_pk_bf16_f32 %0, %1, %2" : "=v"(r) : "v"(lo), "v"(hi));
    return r;
}

// ---------------- K1: sharded hist (+rank) || M-fold || encoder || swizzles ----------------
// LEAN branches only (round-11 lesson: VGPR/LDS alloc is per-kernel; the
// fattest branch taxes every block).
__global__ __launch_bounds__(256) void k1_fused(
    const int* __restrict__ colp, int* __restrict__ cnt8, int* __restrict__ rank,
    const float* __restrict__ edge_w2, const float* __restrict__ node_w1,
    const float* __restrict__ edge_b2,
    float* __restrict__ Mtmp, float* __restrict__ Vtmp,
    const float* __restrict__ x, const float* __restrict__ enc_w,
    const float* __restrict__ enc_b, unsigned short* __restrict__ h,
    const float* __restrict__ edge_w1, const float* __restrict__ node_w2,
    unsigned short* __restrict__ swz) {
    __shared__ float wts[NODE_IN * HID];
    __shared__ float bts[HID];
    __shared__ float xs[64][NODE_IN];
    int b = blockIdx.x, t = threadIdx.x;
    if (b < EDGE_BLOCKS) {
        int e = b * 256 + t;   // exact: 3125*256 = 800000
        int c = colp[e];
        rank[e] = atomicAdd(&cnt8[(size_t)(b & 7) * N_NODES + c], 1);
    } else if (b < EDGE_BLOCKS + MFOLD_BLOCKS) {
        int d = (b - EDGE_BLOCKS) * 256 + t;     // exact: 192*256 = 49152 = 3*16384
        int L = d / 16384, rem = d & 16383;
        int k = rem >> 7, n = rem & 127;
        const float* w2  = edge_w2 + (size_t)L * 16384;
        const float* w1b = node_w1 + (size_t)L * 32768 + 16384;   // bottom-half rows
        float acc = 0.f;
        #pragma unroll 4
        for (int j = 0; j < 128; j++) acc += w2[k * 128 + j] * w1b[j * 128 + n];
        Mtmp[d] = acc;
        if (k == 0) {
            const float* b2 = edge_b2 + (size_t)L * 128;
            float vv = 0.f;
            #pragma unroll 4
            for (int j = 0; j < 128; j++) vv += b2[j] * w1b[j * 128 + n];
            Vtmp[L * 128 + n] = vv;
        }
    } else if (b < EDGE_BLOCKS + MFOLD_BLOCKS + NODE_TILES) {
        // encoder: h = x @ enc_w + enc_b (bf16 store)
        int b2 = b - EDGE_BLOCKS - MFOLD_BLOCKS;   // 0..781
        int n0 = b2 * 64;
        for (int i = t; i < NODE_IN * HID; i += 256) wts[i] = enc_w[i];
        if (t < HID) bts[t] = enc_b[t];
        for (int i = t; i < 64 * NODE_IN; i += 256) {
            int nl = i >> 4, ii = i & 15;
            int n = n0 + nl;
            xs[nl][ii] = (n < N_NODES) ? x[n * NODE_IN + ii] : 0.f;
        }
        __syncthreads();
        for (int o = t; o < 64 * HID; o += 256) {
            int nl = o >> 7, cc = o & 127;
            float acc = bts[cc];
            #pragma unroll
            for (int i = 0; i < NODE_IN; i++) acc += xs[nl][i] * wts[i * HID + cc];
            int n = n0 + nl;
            if (n < N_NODES) h[n * HID + cc] = f2bf(acc);
        }
    } else {
        // Mtmp-independent weight swizzles: edge w1cat + node w2
        int d = (b - EDGE_BLOCKS - MFOLD_BLOCKS - NODE_TILES) * 256 + t;  // < 147456 exact
        int L = d / 49152, rem2 = d - L * 49152;
        unsigned short* base = swz + L * 98304;
        if (rem2 < 32768) {
            const float* w1 = edge_w1 + (size_t)L * 32768;
            int j = rem2 & 7, ll = (rem2 >> 3) & 63, tt = rem2 >> 9;
            int nt = tt & 15, kt = tt >> 4;
            int k = kt * 32 + ((ll >> 4) << 3) + j;
            int cc = nt * 16 + (ll & 15);
            float v = (cc < 128) ? w1[k * 128 + cc] : w1[(128 + k) * 128 + (cc - 128)];
            base[rem2] = f2bf(v);
        } else {
            int d2 = rem2 - 32768;   // [0,16384): node w2
            const float* src = node_w2 + (size_t)L * 16384;
            int j = d2 & 7, ll = (d2 >> 3) & 63, tt = d2 >> 9;
            int nt = tt & 7, kt = tt >> 3;
            int k = kt * 32 + ((ll >> 4) << 3) + j, n = (nt << 4) + (ll & 15);
            base[81920 + d2] = f2bf(src[k * 128 + n]);
        }
    }
}

// ---------------- K2a: shard-reduce + scan1 || w1m swizzle || S/D layer-0 ----------------
// The SD-MFMA branch lives here (not in k3): k2a's other branches total only
// 580 blocks, so the per-kernel VGPR/LDS tax of the fat branch is immaterial,
// while k3's 3125 scatter blocks run lean at full occupancy.
__global__ __launch_bounds__(256) void k2a_scan_swz_sd(
    const int* __restrict__ cnt8, int* __restrict__ base8, int* __restrict__ cntt,
    int* __restrict__ ex, int* __restrict__ bsums,
    const float* __restrict__ node_w1, const float* __restrict__ Mtmp,
    unsigned short* __restrict__ swz,
    const unsigned short* __restrict__ h, const unsigned short* __restrict__ w1c,
    const float* __restrict__ eb1,
    unsigned short* __restrict__ S, unsigned short* __restrict__ D) {
    __shared__ int s[256];
    __shared__ unsigned short hs[64][136];
    int b = blockIdx.x, t = threadIdx.x;
    if (b < SCAN_BLOCKS) {
        int i = b * 256 + t;
        int tot = 0;
        if (i < N_NODES) {
            #pragma unroll
            for (int s2 = 0; s2 < 8; s2++) {
                int v = cnt8[(size_t)s2 * N_NODES + i];
                base8[(size_t)s2 * N_NODES + i] = tot;
                tot += v;
            }
            cntt[i] = tot;
        }
        s[t] = tot;
        __syncthreads();
        for (int off = 1; off < 256; off <<= 1) {
            int u = (t >= off) ? s[t - off] : 0;
            __syncthreads();
            s[t] += u;
            __syncthreads();
        }
        if (i < N_NODES) ex[i] = s[t] - tot;
        if (t == 255) bsums[b] = s[255];
    } else if (b < SCAN_BLOCKS + SWZB_BLOCKS) {
        int d = (b - SCAN_BLOCKS) * 256 + t;   // < 98304 exact
        int L = d / 32768, d2 = d - L * 32768;
        unsigned short* base = swz + L * 98304;
        int j = d2 & 7, ll = (d2 >> 3) & 63, tt = d2 >> 9;
        int nt = tt & 7, kt = tt >> 3;
        int k = kt * 32 + ((ll >> 4) << 3) + j, n = (nt << 4) + (ll & 15);
        float v = (k < 128) ? node_w1[(size_t)L * 32768 + k * 128 + n]
                            : Mtmp[(size_t)L * 16384 + (k - 128) * 128 + n];
        base[49152 + d2] = f2bf(v);
    } else {
        // S/D for layer 0 from h (D gets +edge_b1[0] folded)
        int b2 = b - SCAN_BLOCKS - SWZB_BLOCKS;   // 0..781
        int wave = t >> 6, l = t & 63, q = l >> 4, l16 = l & 15;
        int nt0s = wave * 4;
        int n0 = b2 * 64;
        for (int i = t; i < 64 * 16; i += 256) {
            int nl = i >> 4, li = i & 15;
            int n = n0 + nl;
            short8 v = (short8){0, 0, 0, 0, 0, 0, 0, 0};
            if (n < N_NODES) v = *(const short8*)(h + (size_t)n * HID + li * 8);
            *(short8*)&hs[nl][li * 8] = v;
        }
        short8 wr[4][4];
        #pragma unroll
        for (int kt = 0; kt < 4; kt++)
            #pragma unroll
            for (int i = 0; i < 4; i++)
                wr[kt][i] = *(const short8*)(w1c + ((kt * 16 + nt0s + i) * 64 + l) * 8);
        __syncthreads();

        f32x4 acc[4][4];
        #pragma unroll
        for (int g = 0; g < 4; g++)
            #pragma unroll
            for (int i = 0; i < 4; i++) acc[g][i] = (f32x4){0.f, 0.f, 0.f, 0.f};
        #pragma unroll
        for (int kt = 0; kt < 4; kt++) {
            #pragma unroll
            for (int g = 0; g < 4; g++) {
                short8 a = *(const short8*)&hs[g * 16 + l16][kt * 32 + q * 8];
                #pragma unroll
                for (int i = 0; i < 4; i++)
                    acc[g][i] = __builtin_amdgcn_mfma_f32_16x16x32_bf16(a, wr[kt][i], acc[g][i], 0, 0, 0);
            }
        }
        #pragma unroll
        for (int i = 0; i < 4; i++) {
            int cc = (nt0s + i) * 16 + l16;
            float badd = 0.f;
            if (cc >= 128) badd = eb1[cc - 128];
            #pragma unroll
            for (int g = 0; g < 4; g++)
                #pragma unroll
                for (int r = 0; r < 4; r++) {
                    int n = n0 + g * 16 + q * 4 + r;
                    if (n < N_NODES) {
                        unsigned short v = f2bf(acc[g][i][r] + badd);
                        if (cc < 128) S[n * HID + cc] = v;
                        else          D[n * HID + (cc - 128)] = v;
                    }
                }
        }
    }
}

// ---------------- K3: LEAN scatter only (+ex2); pos = ex + ls + base8[shard] + rank ----------------
__global__ __launch_bounds__(256) void k3_scatter(
    const int* __restrict__ rowp, const int* __restrict__ colp,
    const int* __restrict__ ex, const int* __restrict__ bsums,
    const int* __restrict__ rank, const int* __restrict__ base8,
    int* __restrict__ rsrt, int* __restrict__ ex2) {
    __shared__ int sc[256];
    __shared__ int ls[SCAN_BLOCKS];
    int b = blockIdx.x, t = threadIdx.x;
    int v = (t < SCAN_BLOCKS) ? bsums[t] : 0;
    sc[t] = v;
    __syncthreads();
    for (int off = 1; off < 256; off <<= 1) {
        int u = (t >= off) ? sc[t - off] : 0;
        __syncthreads();
        sc[t] += u;
        __syncthreads();
    }
    if (t < SCAN_BLOCKS) ls[t] = sc[t] - v;
    __syncthreads();

    if (b < SCAN_BLOCKS) {
        int i = b * 256 + t;
        if (i < N_NODES) ex2[i] = ex[i] + ls[b];
    }
    int e = b * 256 + t;   // exact 800000
    int c = colp[e];
    int sh = b & 7;        // shard = block residue (matches k1 hist)
    int pos = ex[c] + ls[c >> 8] + base8[(size_t)sh * N_NODES + c] + rank[e];
    rsrt[pos] = rowp[e];   // dest implied by position
}

// ---------------- edge: 32-lane dest groups, depth-4 2-stage pipeline ----------------
__global__ __launch_bounds__(256, 8) void edge_kernel(
    const unsigned short* __restrict__ S, const unsigned short* __restrict__ D,
    const int* __restrict__ rsrt, const int* __restrict__ ex2,
    unsigned short* __restrict__ aggB)
{
    int t = threadIdx.x;
    int g32 = t >> 5, ch = t & 31;   // 8 dests/block; lane covers channels ch*4..+3

    // XCD-chunked bijective mapping over EDBLOCKS dest-blocks
    const int q = EDBLOCKS / 8, r = EDBLOCKS % 8;   // 781, 2
    int xcd = blockIdx.x & 7, slot = blockIdx.x >> 3;
    int cntx = q + (xcd < r);
    if (slot >= cntx) return;
    int myb = xcd * q + (xcd < r ? xcd : r) + slot;

    int d = myb * 8 + g32;   // exact: 6250*8 = 50000
    int e0 = ex2[d];
    int e1 = (d < N_NODES - 1) ? ex2[d + 1] : N_EDGES;

    int2 dv = *(const int2*)(D + (size_t)d * HID + ch * 4);
    float dr0 = bfu_lo((unsigned int)dv.x), dr1 = bfu_hi((unsigned int)dv.x);
    float dr2 = bfu_lo((unsigned int)dv.y), dr3 = bfu_hi((unsigned int)dv.y);
    float a0 = 0.f, a1 = 0.f, a2 = 0.f, a3 = 0.f;

    auto Srow = [&](int rn) -> int2 {
        return *(const int2*)(S + (size_t)rn * HID + ch * 4);
    };
    auto accum = [&](int2 sv) {
        float v0 = bfu_lo((unsigned int)sv.x) + dr0;
        float v1 = bfu_hi((unsigned int)sv.x) + dr1;
        float v2 = bfu_lo((unsigned int)sv.y) + dr2;
        float v3 = bfu_hi((unsigned int)sv.y) + dr3;
        a0 += v0 > 0.f ? v0 : 0.f;
        a1 += v1 > 0.f ? v1 : 0.f;
        a2 += v2 > 0.f ? v2 : 0.f;
        a3 += v3 > 0.f ? v3 : 0.f;
    };
    const int2 z = make_int2(0, 0);

    int2 c0 = z, c1 = z, c2 = z, c3 = z;
    int rb0 = 0, rb1 = 0, rb2 = 0, rb3 = 0;
    {
        int ra0 = (e0     < e1) ? rsrt[e0]     : 0;
        int ra1 = (e0 + 1 < e1) ? rsrt[e0 + 1] : 0;
        int ra2 = (e0 + 2 < e1) ? rsrt[e0 + 2] : 0;
        int ra3 = (e0 + 3 < e1) ? rsrt[e0 + 3] : 0;
        rb0 = (e0 + 4 < e1) ? rsrt[e0 + 4] : 0;
        rb1 = (e0 + 5 < e1) ? rsrt[e0 + 5] : 0;
        rb2 = (e0 + 6 < e1) ? rsrt[e0 + 6] : 0;
        rb3 = (e0 + 7 < e1) ? rsrt[e0 + 7] : 0;
        if (e0     < e1) c0 = Srow(ra0);
        if (e0 + 1 < e1) c1 = Srow(ra1);
        if (e0 + 2 < e1) c2 = Srow(ra2);
        if (e0 + 3 < e1) c3 = Srow(ra3);
    }

    int e = e0;
    while (e + 12 <= e1) {
        int m0 = rsrt[e + 8], m1 = rsrt[e + 9];
        int2 f0 = Srow(rb0), f1 = Srow(rb1);
        accum(c0); accum(c1);
        int m2 = rsrt[e + 10], m3 = rsrt[e + 11];
        int2 f2 = Srow(rb2), f3 = Srow(rb3);
        accum(c2); accum(c3);
        c0 = f0; c1 = f1; c2 = f2; c3 = f3;
        rb0 = m0; rb1 = m1; rb2 = m2; rb3 = m3;
        e += 4;
    }
    int rem = e1 - e;   // 0..11
    if (rem > 0) accum(c0);
    if (rem > 1) accum(c1);
    if (rem > 2) accum(c2);
    if (rem > 3) accum(c3);
    if (rem > 4) accum(Srow(rb0));
    if (rem > 5) accum(Srow(rb1));
    if (rem > 6) accum(Srow(rb2));
    if (rem > 7) accum(Srow(rb3));
    for (int j = 8; j < rem; j++) accum(Srow(rsrt[e + j]));

    int2 o = make_int2((int)cvt_pk_bf16(a0, a1), (int)cvt_pk_bf16(a2, a3));
    *(int2*)(aggB + (size_t)d * HID + ch * 4) = o;
}

// ---------------- node MLP (folded GEMM1) + residual + (next S/D | decoder) ----------------
template<int LAST>
__global__ __launch_bounds__(256, 4) void node_kernel(
    unsigned short* __restrict__ h, const unsigned short* __restrict__ aggB,
    const int* __restrict__ cnt,
    const unsigned short* __restrict__ w1m_s, const float* __restrict__ b1,
    const float* __restrict__ vfold,
    const unsigned short* __restrict__ w2s, const float* __restrict__ b2,
    const unsigned short* __restrict__ w1c_next, const float* __restrict__ eb1n,
    unsigned short* __restrict__ S, unsigned short* __restrict__ D,
    const float* __restrict__ dec_w, const float* __restrict__ dec_b, float* __restrict__ out)
{
    __shared__ unsigned short in_h[64][136];   // old h -> new h after residual
    __shared__ unsigned short in_a[64][136];   // bf16 agg; reused as hid after GEMM1
    __shared__ int cnt_s[64];
    __shared__ float dw[HID * NODE_OUT];
    __shared__ float db[NODE_OUT];
    int t = threadIdx.x, wave = t >> 6, l = t & 63, q = l >> 4, l16 = l & 15;
    int nt0 = wave * 2, nt0s = wave * 4;
    int n0 = blockIdx.x * 64;

    if (LAST) {
        for (int i = t; i < HID * NODE_OUT; i += 256) dw[i] = dec_w[i];
        if (t < NODE_OUT) db[t] = dec_b[t];
    }

    // stage: h -> in_h, aggB(bf16) -> in_a, cnt
    #pragma unroll
    for (int it = 0; it < 8; it++) {
        int g = it * 256 + t;
        int nl = g >> 5, sub = g & 31, half = sub >> 4, li = sub & 15;
        int n = n0 + nl;
        short8 v = (short8){0, 0, 0, 0, 0, 0, 0, 0};
        if (n < N_NODES) {
            if (half == 0) v = *(const short8*)(h + (size_t)n * HID + li * 8);
            else           v = *(const short8*)(aggB + (size_t)n * HID + li * 8);
        }
        if (half == 0) *(short8*)&in_h[nl][li * 8] = v;
        else           *(short8*)&in_a[nl][li * 8] = v;
    }
    if (t < 64) cnt_s[t] = (n0 + t < N_NODES) ? cnt[n0 + t] : 0;
    __syncthreads();

    float b1r0 = b1[nt0 * 16 + l16], b1r1 = b1[(nt0 + 1) * 16 + l16];
    float vr0 = vfold[nt0 * 16 + l16], vr1 = vfold[(nt0 + 1) * 16 + l16];
    float b2r0 = b2[nt0 * 16 + l16], b2r1 = b2[(nt0 + 1) * 16 + l16];

    // GEMM1 (K=256, B = [W1top; M] folded): h@W1top + agg@M
    f32x4 acc[4][2];
    #pragma unroll
    for (int g = 0; g < 4; g++)
        #pragma unroll
        for (int j = 0; j < 2; j++) acc[g][j] = (f32x4){0.f, 0.f, 0.f, 0.f};
    #pragma unroll
    for (int kt = 0; kt < 8; kt++) {
        short8 b0 = *(const short8*)(w1m_s + ((kt * 8 + nt0)     * 64 + l) * 8);
        short8 b1v = *(const short8*)(w1m_s + ((kt * 8 + nt0 + 1) * 64 + l) * 8);
        #pragma unroll
        for (int g = 0; g < 4; g++) {
            short8 a = (kt < 4) ? *(const short8*)&in_h[g * 16 + l16][kt * 32 + q * 8]
                                : *(const short8*)&in_a[g * 16 + l16][(kt - 4) * 32 + q * 8];
            acc[g][0] = __builtin_amdgcn_mfma_f32_16x16x32_bf16(a, b0, acc[g][0], 0, 0, 0);
            acc[g][1] = __builtin_amdgcn_mfma_f32_16x16x32_bf16(a, b1v, acc[g][1], 0, 0, 0);
        }
    }
    __syncthreads();   // all in_a reads complete before hid overwrite

    // epilogue: + b1 + deg*v -> relu -> hid (aliases in_a)
    #pragma unroll
    for (int j = 0; j < 2; j++) {
        float bv = j ? b1r1 : b1r0;
        float vv = j ? vr1 : vr0;
        #pragma unroll
        for (int g = 0; g < 4; g++)
            #pragma unroll
            for (int r = 0; r < 4; r++) {
                int m2 = g * 16 + q * 4 + r;
                float v = acc[g][j][r] + bv + (float)cnt_s[m2] * vv;
                v = v > 0.f ? v : 0.f;
                in_a[m2][(nt0 + j) * 16 + l16] = f2bf(v);
            }
    }
    __syncthreads();

    // GEMM2n (K=128) -> residual -> h + in_h
    f32x4 acc2[4][2];
    #pragma unroll
    for (int g = 0; g < 4; g++)
        #pragma unroll
        for (int j = 0; j < 2; j++) acc2[g][j] = (f32x4){0.f, 0.f, 0.f, 0.f};
    #pragma unroll
    for (int kt = 0; kt < 4; kt++) {
        short8 b0 = *(const short8*)(w2s + ((kt * 8 + nt0)     * 64 + l) * 8);
        short8 b1v = *(const short8*)(w2s + ((kt * 8 + nt0 + 1) * 64 + l) * 8);
        #pragma unroll
        for (int g = 0; g < 4; g++) {
            short8 a = *(const short8*)&in_a[g * 16 + l16][kt * 32 + q * 8];
            acc2[g][0] = __builtin_amdgcn_mfma_f32_16x16x32_bf16(a, b0, acc2[g][0], 0, 0, 0);
            acc2[g][1] = __builtin_amdgcn_mfma_f32_16x16x32_bf16(a, b1v, acc2[g][1], 0, 0, 0);
        }
    }
    #pragma unroll
    for (int j = 0; j < 2; j++) {
        float bv = j ? b2r1 : b2r0;
        #pragma unroll
        for (int g = 0; g < 4; g++)
            #pragma unroll
            for (int r = 0; r < 4; r++) {
                float v = acc2[g][j][r] + bv;
                int m2 = g * 16 + q * 4 + r;
                int n = n0 + m2;
                if (n < N_NODES) {
                    int c = (nt0 + j) * 16 + l16;
                    unsigned short nh = f2bf(bf2f(in_h[m2][c]) + v);   // residual (same-thread cell)
                    if (!LAST) h[n * HID + c] = nh;
                    in_h[m2][c] = nh;
                }
            }
    }
    __syncthreads();

    if (!LAST) {
        // next-layer S/D from new h (in_h); D gets +edge_b1[L+1] folded
        #pragma unroll
        for (int p = 0; p < 2; p++) {
            short8 wr[4][2];
            #pragma unroll
            for (int kt = 0; kt < 4; kt++) {
                wr[kt][0] = *(const short8*)(w1c_next + ((kt * 16 + nt0s + p * 2)     * 64 + l) * 8);
                wr[kt][1] = *(const short8*)(w1c_next + ((kt * 16 + nt0s + p * 2 + 1) * 64 + l) * 8);
            }
            f32x4 accs[4][2];
            #pragma unroll
            for (int g = 0; g < 4; g++)
                #pragma unroll
                for (int i = 0; i < 2; i++) accs[g][i] = (f32x4){0.f, 0.f, 0.f, 0.f};
            #pragma unroll
            for (int kt = 0; kt < 4; kt++) {
                #pragma unroll
                for (int g = 0; g < 4; g++) {
                    short8 a = *(const short8*)&in_h[g * 16 + l16][kt * 32 + q * 8];
                    accs[g][0] = __builtin_amdgcn_mfma_f32_16x16x32_bf16(a, wr[kt][0], accs[g][0], 0, 0, 0);
                    accs[g][1] = __builtin_amdgcn_mfma_f32_16x16x32_bf16(a, wr[kt][1], accs[g][1], 0, 0, 0);
                }
            }
            #pragma unroll
            for (int i = 0; i < 2; i++) {
                int c = (nt0s + p * 2 + i) * 16 + l16;
                float badd = 0.f;
                if (c >= 128) badd = eb1n[c - 128];
                #pragma unroll
                for (int g = 0; g < 4; g++)
                    #pragma unroll
                    for (int r = 0; r < 4; r++) {
                        int n = n0 + g * 16 + q * 4 + r;
                        if (n < N_NODES) {
                            unsigned short v = f2bf(accs[g][i][r] + badd);
                            if (c < 128) S[n * HID + c] = v;
                            else         D[n * HID + (c - 128)] = v;
                        }
                    }
            }
        }
    } else {
        // decoder: out = new_h @ dec_w + dec_b
        if (t < 64 * NODE_OUT) {
            int nl = t / 3, o = t - 3 * nl;
            int n = n0 + nl;
            if (n < N_NODES) {
                float a = db[o];
                #pragma unroll 4
                for (int k = 0; k < HID; k++) a += bf2f(in_h[nl][k]) * dw[k * 3 + o];
                out[n * 3 + o] = a;
            }
        }
    }
}

extern "C" void kernel_launch(void* const* d_in, const int* in_sizes, int n_in,
                              void* d_out, int out_size, void* d_ws, size_t ws_size,
                              hipStream_t stream) {
    const float* x       = (const float*)d_in[0];
    const int*   ei      = (const int*)d_in[1];
    const float* enc_w   = (const float*)d_in[2];
    const float* enc_b   = (const float*)d_in[3];
    const float* dec_w   = (const float*)d_in[4];
    const float* dec_b   = (const float*)d_in[5];
    const float* edge_w1 = (const float*)d_in[6];
    const float* edge_b1 = (const float*)d_in[7];
    const float* edge_w2 = (const float*)d_in[8];
    const float* edge_b2 = (const float*)d_in[9];
    const float* node_w1 = (const float*)d_in[10];
    const float* node_b1 = (const float*)d_in[11];
    const float* node_w2 = (const float*)d_in[12];
    const float* node_b2 = (const float*)d_in[13];

    char* ws = (char*)d_ws;
    unsigned short* h    = (unsigned short*)ws;                    // 12.8 MB
    unsigned short* aggB = (unsigned short*)(ws + 12800000);       // 12.8 MB (bf16 agg)
    unsigned short* swz  = (unsigned short*)(ws + 25600000);       // 589,824 B
    int* cnt8            = (int*)(ws + 26189824);                  // 1.6 MB (8 shards)
    int* base8           = (int*)(ws + 27789824);                  // 1.6 MB
    int* cntt            = (int*)(ws + 29389824);                  // 200,000 B (totals)
    int* ex              = (int*)(ws + 29589824);                  // 200,000 B
    int* bsums           = (int*)(ws + 29789824);                  // 1,024 B
    int* rsrt            = (int*)(ws + 29790848);                  // 3.2 MB
    unsigned short* Sbuf = (unsigned short*)(ws + 32990848);       // 12.8 MB
    unsigned short* Dbuf = (unsigned short*)(ws + 45790848);       // 12.8 MB
    float* Mtmp          = (float*)(ws + 58590848);                // 196,608 B
    float* Vtmp          = (float*)(ws + 58787456);                // 1,536 B
    int* ex2             = (int*)(ws + 58788992);                  // 200,000 B
    int* rank            = (int*)(ws + 58988992);                  // 3.2 MB -> end 62,188,992

    const int* rowp = ei;            // edge_index[0] = source
    const int* colp = ei + N_EDGES;  // edge_index[1] = destination

    hipMemsetAsync(cnt8, 0, (size_t)8 * N_NODES * 4, stream);

    k1_fused<<<EDGE_BLOCKS + MFOLD_BLOCKS + NODE_TILES + SWZA_BLOCKS, 256, 0, stream>>>(
        colp, cnt8, rank, edge_w2, node_w1, edge_b2, Mtmp, Vtmp,
        x, enc_w, enc_b, h, edge_w1, node_w2, swz);
    k2a_scan_swz_sd<<<SCAN_BLOCKS + SWZB_BLOCKS + NODE_TILES, 256, 0, stream>>>(
        cnt8, base8, cntt, ex, bsums, node_w1, Mtmp, swz,
        h, swz /*L0 w1cat*/, edge_b1 /*fold L0 bias into D*/, Sbuf, Dbuf);
    k3_scatter<<<EDGE_BLOCKS, 256, 0, stream>>>(
        rowp, colp, ex, bsums, rank, base8, rsrt, ex2);

    for (int L = 0; L < 3; L++) {
        unsigned short* base = swz + (size_t)L * 98304;
        unsigned short* next = swz + (size_t)(L + 1) * 98304;   // w1cat of next layer
        edge_kernel<<<6256, 256, 0, stream>>>(Sbuf, Dbuf, rsrt, ex2, aggB);
        if (L < 2) {
            node_kernel<0><<<NODE_TILES, 256, 0, stream>>>(
                h, aggB, cntt,
                base + 49152, node_b1 + (size_t)L * HID, Vtmp + (size_t)L * HID,
                base + 81920, node_b2 + (size_t)L * HID,
                next, edge_b1 + (size_t)(L + 1) * HID, Sbuf, Dbuf, dec_w, dec_b, (float*)d_out);
        } else {
            node_kernel<1><<<NODE_TILES, 256, 0, stream>>>(
                h, aggB, cntt,
                base + 49152, node_b1 + (size_t)L * HID, Vtmp + (size_t)L * HID,
                base + 81920, node_b2 + (size_t)L * HID,
                base /*unused*/, edge_b1 /*unused*/, Sbuf, Dbuf, dec_w, dec_b, (float*)d_out);
        }
    }
}